// Round 10
// baseline (1992.522 us; speedup 1.0000x reference)
//
#include <hip/hip_runtime.h>
#include <stdint.h>

typedef unsigned short u16;
typedef __attribute__((ext_vector_type(8))) short bfrag;   // 8 bf16 = 4 VGPR
typedef __attribute__((ext_vector_type(4))) float f32x4;   // MFMA C/D

__device__ __forceinline__ uint32_t pack2bf(float x, float y) {
  uint32_t bx = __float_as_uint(x), by = __float_as_uint(y);
  bx += 0x7fffu + ((bx >> 16) & 1u);
  by += 0x7fffu + ((by >> 16) & 1u);
  return (bx >> 16) | (by & 0xffff0000u);
}
__device__ __forceinline__ u16 f2bf(float x) {
  uint32_t b = __float_as_uint(x);
  b += 0x7fffu + ((b >> 16) & 1u);
  return (u16)(b >> 16);
}
__device__ __forceinline__ float bflo(uint32_t p) { return __uint_as_float(p << 16); }
__device__ __forceinline__ float bfhi(uint32_t p) { return __uint_as_float(p & 0xffff0000u); }

// ---- x (f32) -> bf16 pairs, SLICED layout: X[s][node][8 u32], s = feat/16 ----
__global__ void k_cvt_x(const float* __restrict__ x, uint32_t* __restrict__ xb,
                        int n4, int n) {
  int i = blockIdx.x * blockDim.x + threadIdx.x;
  if (i >= n4) return;
  int node = i >> 5, q = i & 31;         // q: u32-pair index (4 floats)
  float4 v = ((const float4*)x)[i];
  int s = q >> 2, fl = (q & 3) << 1;
  size_t a = ((size_t)s * n + node) * 8 + fl;
  xb[a]     = pack2bf(v.x, v.y);
  xb[a + 1] = pack2bf(v.z, v.w);
}

// ---- W[l][k][c] (f32) -> Wt[l][br][c][k] (bf16) ----
__global__ void k_cvt_w(const float* __restrict__ wp, const float* __restrict__ wn,
                        u16* __restrict__ wt, int total) {
  int i = blockIdx.x * blockDim.x + threadIdx.x;
  if (i >= total) return;
  int l = i >> 15;
  int rem = i & 32767;
  int br = rem >> 14;
  int rem2 = rem & 16383;
  int c = rem2 >> 7;
  int k = rem2 & 127;
  const float* w = br ? wn : wp;
  wt[i] = f2bf(w[l * 16384 + k * 128 + c]);
}

// ---- per-(node,sub,sign) slot counts: slot = d*8 + (e&3)*2 + sign ----
__global__ void k_count(const int* __restrict__ ei, const float* __restrict__ ew,
                        int* __restrict__ cnt, int E) {
  int e = blockIdx.x * blockDim.x + threadIdx.x;
  if (e >= E) return;
  float w = ew[e];
  if (w == 0.f) return;
  int d = ei[E + e];
  int slot = (d << 3) | ((e & 3) << 1) | (w < 0.f ? 1 : 0);
  atomicAdd(&cnt[slot], 1);
}

// ---- exclusive scan of cnt[0..M) : 3-kernel hierarchical (M = 8N) ----
__global__ void k_scan1(const int* __restrict__ cnt, int* __restrict__ offs,
                        int* __restrict__ part, int M) {
  __shared__ int sh[1024];
  int t = threadIdx.x;
  int i = blockIdx.x * 1024 + t;
  int v = (i < M) ? cnt[i] : 0;
  sh[t] = v;
  __syncthreads();
  for (int off = 1; off < 1024; off <<= 1) {
    int add = (t >= off) ? sh[t - off] : 0;
    __syncthreads();
    sh[t] += add;
    __syncthreads();
  }
  if (i < M) offs[i] = sh[t] - v;   // exclusive within block
  if (t == 1023) part[blockIdx.x] = sh[1023];
}
// parallel scan of block partials; writes offs[M]=total + 32 zero pad records
__global__ void k_scan2(int* __restrict__ part, int* __restrict__ offs,
                        uint32_t* __restrict__ rec, int nb, int M) {
  __shared__ int sh[1024];
  int t = threadIdx.x;
  int v = (t < nb) ? part[t] : 0;
  sh[t] = v;
  __syncthreads();
  for (int off = 1; off < 1024; off <<= 1) {
    int add = (t >= off) ? sh[t - off] : 0;
    __syncthreads();
    sh[t] += add;
    __syncthreads();
  }
  if (t < nb) part[t] = sh[t] - v;   // exclusive
  if (t == 1023) {
    int run = sh[1023];
    offs[M] = run;
    for (int i = 0; i < 32; ++i) rec[run + i] = 0u;
  }
}
// per-node: slot bases -> cur, node boundary -> bnd, dpn = {+1/sqrt(1+degp), -1/sqrt(1+degn)}
__global__ void k_scan3(const int* __restrict__ offs, const int* __restrict__ part,
                        int* __restrict__ cur, int* __restrict__ bnd,
                        float* __restrict__ dpn, int n, int M) {
  int d = blockIdx.x * blockDim.x + threadIdx.x;
  if (d >= n) return;
  int o[9];
#pragma unroll
  for (int k = 0; k < 8; ++k) {
    int idx = d * 8 + k;
    o[k] = offs[idx] + part[idx >> 10];
  }
  int idx9 = d * 8 + 8;
  o[8] = (idx9 < M) ? (offs[idx9] + part[idx9 >> 10]) : offs[M];
#pragma unroll
  for (int k = 0; k < 8; ++k) cur[d * 8 + k] = o[k];
  bnd[d] = o[0];
  if (d == 0) bnd[n] = offs[M];
  int degp = 0, degn = 0;
#pragma unroll
  for (int k = 0; k < 8; k += 2) degp += o[k + 1] - o[k];
#pragma unroll
  for (int k = 1; k < 8; k += 2) degn += ((k == 7) ? o[8] : o[k + 1]) - o[k];
  dpn[2 * d]     =  rsqrtf(1.f + (float)degp);
  dpn[2 * d + 1] = -rsqrtf(1.f + (float)degn);
}

// ---- build dst-grouped records {src | sign<<31} (4 B), slot-sharded ----
__global__ void k_build(const int* __restrict__ ei, const float* __restrict__ ew,
                        int* __restrict__ cur, uint32_t* __restrict__ rec, int E) {
  int e = blockIdx.x * blockDim.x + threadIdx.x;
  if (e >= E) return;
  float w = ew[e];
  if (w == 0.f) return;
  int s = ei[e], d = ei[E + e];
  int sign = (w < 0.f) ? 1 : 0;
  int slot = (d << 3) | ((e & 3) << 1) | sign;
  int p = atomicAdd(&cur[slot], 1);
  rec[p] = (uint32_t)s | ((uint32_t)sign << 31);
}

// ---- feature-sliced aggregation: block = (slice = blockIdx&7, 4 dsts) ----
// wave = 8 edge-units x 8 feature-lanes; X slice (3.2MB) stays L2-resident per XCD.
__global__ __launch_bounds__(256) void k_agg(
    const uint32_t* __restrict__ X, const int* __restrict__ bnd,
    const uint32_t* __restrict__ rec, const float* __restrict__ dpn,
    uint32_t* __restrict__ up, uint32_t* __restrict__ un, int n) {
  int slice = blockIdx.x & 7, grp = blockIdx.x >> 3;
  int wv = threadIdx.x >> 6, lane = threadIdx.x & 63;
  int nd = grp * 4 + wv;
  if (nd >= n) return;
  int eu = lane >> 3, fl = lane & 7;
  const uint32_t* xs = X + (size_t)slice * n * 8;
  int beg = bnd[nd], end = bnd[nd + 1];
  float ap0 = 0.f, ap1 = 0.f, an0 = 0.f, an1 = 0.f;
  for (int j = beg; j < end; j += 32) {
    uint32_t rr[4]; uint32_t pk[4]; float dd[4];
#pragma unroll
    for (int u = 0; u < 4; ++u)
      rr[u] = __builtin_nontemporal_load(rec + j + u * 8 + eu);  // over-read: 32 pads
#pragma unroll
    for (int u = 0; u < 4; ++u)
      pk[u] = xs[(size_t)(rr[u] & 0x7fffffffu) * 8 + fl];
#pragma unroll
    for (int u = 0; u < 4; ++u)
      dd[u] = (j + u * 8 + eu < end)
                ? dpn[((rr[u] & 0x7fffffffu) << 1) | (rr[u] >> 31)] : 0.f;
#pragma unroll
    for (int u = 0; u < 4; ++u) {
      float np = fmaxf(dd[u], 0.f), nn = fmaxf(-dd[u], 0.f);
      float v0 = bflo(pk[u]), v1 = bfhi(pk[u]);
      ap0 = fmaf(np, v0, ap0); ap1 = fmaf(np, v1, ap1);
      an0 = fmaf(nn, v0, an0); an1 = fmaf(nn, v1, an1);
    }
  }
#pragma unroll
  for (int m = 8; m < 64; m <<= 1) {  // reduce across edge-units (lane bits 3..5)
    ap0 += __shfl_xor(ap0, m, 64);
    ap1 += __shfl_xor(ap1, m, 64);
    an0 += __shfl_xor(an0, m, 64);
    an1 += __shfl_xor(an1, m, 64);
  }
  if (lane < 8) {
    float dpd = dpn[2 * nd], dnd = -dpn[2 * nd + 1];
    float sp = dpd * dpd, sn = dnd * dnd;  // self_norm = 1/(1+deg)
    uint32_t hk = xs[(size_t)nd * 8 + fl];
    float h0 = bflo(hk), h1 = bfhi(hk);
    size_t a = ((size_t)slice * n + nd) * 8 + fl;
    // U = dpd*ap + sp*h  (per-edge coeff was dp[s]; dst factor folded here)
    up[a] = pack2bf(fmaf(sp, h0, dpd * ap0), fmaf(sp, h1, dpd * ap1));
    un[a] = pack2bf(fmaf(sn, h0, dnd * an0), fmaf(sn, h1, dnd * an1));
  }
}

// ---- fused dual GEMM + bias + relu-diff, persistent blocks; sliced U/V/X ----
__global__ __launch_bounds__(256, 2) void k_gemm(
    const short* __restrict__ up, const short* __restrict__ un,
    const u16* __restrict__ wt, const float* __restrict__ bp, const float* __restrict__ bn,
    u16* __restrict__ hout, int nrows, int nchunks) {
  __shared__ __align__(16) u16 wl[32768];  // 64 KB: Wt_pos | Wt_neg, XOR-swizzled
  int t = threadIdx.x;
  for (int i = t; i < 4096; i += 256) {    // 4096 x 16B chunks
    int ci = i & 2047;
    int col = ci >> 4, kc16 = ci & 15;
    int db = (i >> 11) * 32768 + ((col * 256 + kc16 * 16) ^ ((col & 7) << 4));
    *(uint4*)((char*)wl + db) = ((const uint4*)wt)[i];
  }
  __syncthreads();
  int wv = t >> 6, lane = t & 63;
  int l15 = lane & 15, l4 = lane >> 4;
  float vbp[8], vbn[8];
#pragma unroll
  for (int nt = 0; nt < 8; ++nt) {
    vbp[nt] = bp[nt * 16 + l15];
    vbn[nt] = bn[nt * 16 + l15];
  }
  for (int c = blockIdx.x; c < nchunks; c += gridDim.x) {
    int rowbase = c * 128 + wv * 32;
    int r0 = rowbase + l15;      if (r0 >= nrows) r0 = nrows - 1;
    int r1 = rowbase + 16 + l15; if (r1 >= nrows) r1 = nrows - 1;
    f32x4 accP[2][8], accN[2][8];
#pragma unroll
    for (int rt = 0; rt < 2; ++rt)
#pragma unroll
      for (int nt = 0; nt < 8; ++nt) { accP[rt][nt] = (f32x4)(0.f); accN[rt][nt] = (f32x4)(0.f); }
#pragma unroll
    for (int kc = 0; kc < 4; ++kc) {
      int sA = kc * 2 + (l4 >> 1);         // feature-slice of this k-fragment
      int offA = (l4 & 1) * 8;
      bfrag aP0 = *(const bfrag*)(up + ((size_t)sA * nrows + r0) * 16 + offA);
      bfrag aP1 = *(const bfrag*)(up + ((size_t)sA * nrows + r1) * 16 + offA);
      bfrag aN0 = *(const bfrag*)(un + ((size_t)sA * nrows + r0) * 16 + offA);
      bfrag aN1 = *(const bfrag*)(un + ((size_t)sA * nrows + r1) * 16 + offA);
#pragma unroll
      for (int nt = 0; nt < 8; ++nt) {
        int col = nt * 16 + l15;
        int bb = (col * 256 + kc * 64 + l4 * 16) ^ ((col & 7) << 4);
        bfrag bP = *(const bfrag*)((const char*)wl + bb);
        bfrag bN = *(const bfrag*)((const char*)wl + 32768 + bb);
        accP[0][nt] = __builtin_amdgcn_mfma_f32_16x16x32_bf16(aP0, bP, accP[0][nt], 0, 0, 0);
        accP[1][nt] = __builtin_amdgcn_mfma_f32_16x16x32_bf16(aP1, bP, accP[1][nt], 0, 0, 0);
        accN[0][nt] = __builtin_amdgcn_mfma_f32_16x16x32_bf16(aN0, bN, accN[0][nt], 0, 0, 0);
        accN[1][nt] = __builtin_amdgcn_mfma_f32_16x16x32_bf16(aN1, bN, accN[1][nt], 0, 0, 0);
      }
    }
#pragma unroll
    for (int rt = 0; rt < 2; ++rt) {
#pragma unroll
      for (int nt = 0; nt < 8; ++nt) {
#pragma unroll
        for (int r = 0; r < 4; ++r) {
          int row = rowbase + rt * 16 + l4 * 4 + r;
          if (row < nrows) {
            float vp = accP[rt][nt][r] + vbp[nt]; vp = vp > 0.f ? vp : 0.f;
            float vn = accN[rt][nt][r] + vbn[nt]; vn = vn > 0.f ? vn : 0.f;
            hout[((size_t)nt * nrows + row) * 16 + l15] = f2bf(vp - vn);  // sliced X out
          }
        }
      }
    }
  }
}

// ---- mean pool (sliced X reads) ----
__global__ void k_pool(const uint32_t* __restrict__ h, const int* __restrict__ batch,
                       float* __restrict__ pooled, float* __restrict__ gcnt, int n) {
  int gid = blockIdx.x * blockDim.x + threadIdx.x;
  int w = gid >> 6, lane = gid & 63;
  int n0 = w * 8;
  if (n0 >= n) return;
  size_t soff = (size_t)(lane >> 3) * n * 8 + (lane & 7);
  int curg = -1, c = 0;
  float a0 = 0.f, a1 = 0.f;
  for (int i = 0; i < 8; ++i) {
    int nd = n0 + i;
    if (nd >= n) break;
    int g = batch[nd];
    if (g != curg) {
      if (curg >= 0) {
        atomicAdd(&pooled[curg * 128 + 2 * lane], a0);
        atomicAdd(&pooled[curg * 128 + 2 * lane + 1], a1);
        if (lane == 0) atomicAdd(gcnt + curg, (float)c);
      }
      curg = g; a0 = a1 = 0.f; c = 0;
    }
    uint32_t pk = h[soff + (size_t)nd * 8];
    a0 += bflo(pk); a1 += bfhi(pk); ++c;
  }
  if (curg >= 0) {
    atomicAdd(&pooled[curg * 128 + 2 * lane], a0);
    atomicAdd(&pooled[curg * 128 + 2 * lane + 1], a1);
    if (lane == 0) atomicAdd(gcnt + curg, (float)c);
  }
}

// ---- LayerNorm over D=128, one wave per graph ----
__global__ void k_ln(const float* __restrict__ pooled, const float* __restrict__ gcnt,
                     const float* __restrict__ gamma, const float* __restrict__ beta,
                     float* __restrict__ out, int G) {
  int gid = blockIdx.x * blockDim.x + threadIdx.x;
  int g = gid >> 6, lane = gid & 63;
  if (g >= G) return;
  float2 s = ((const float2*)pooled)[g * 64 + lane];
  float cm = fmaxf(gcnt[g], 1.f);
  float v0 = s.x / cm, v1 = s.y / cm;
  float tsum = v0 + v1;
#pragma unroll
  for (int m = 1; m < 64; m <<= 1) tsum += __shfl_xor(tsum, m, 64);
  float mu = tsum * (1.f / 128.f);
  float d0 = v0 - mu, d1 = v1 - mu;
  float q = d0 * d0 + d1 * d1;
#pragma unroll
  for (int m = 1; m < 64; m <<= 1) q += __shfl_xor(q, m, 64);
  float inv = rsqrtf(q * (1.f / 128.f) + 1e-5f);
  int f = 2 * lane;
  out[g * 128 + f]     = d0 * inv * gamma[f]     + beta[f];
  out[g * 128 + f + 1] = d1 * inv * gamma[f + 1] + beta[f + 1];
}

extern "C" void kernel_launch(void* const* d_in, const int* in_sizes, int n_in,
                              void* d_out, int out_size, void* d_ws, size_t ws_size,
                              hipStream_t stream) {
  const float* x     = (const float*)d_in[0];
  const int* ei      = (const int*)d_in[1];   // harness converts int64 -> int32
  const float* ew    = (const float*)d_in[2];
  const int* bt      = (const int*)d_in[3];   // int32
  const float* Wp    = (const float*)d_in[4];
  const float* bp    = (const float*)d_in[5];
  const float* Wn    = (const float*)d_in[6];
  const float* bn    = (const float*)d_in[7];
  const float* gamma = (const float*)d_in[8];
  const float* beta  = (const float*)d_in[9];
  int N = in_sizes[0] / 128;
  int E = in_sizes[1] / 2;
  int L = in_sizes[4] / (128 * 128);
  int G = out_size / 128;
  int M = N * 8;

  char* w = (char*)d_ws;
  auto alloc = [&](size_t bytes) {
    char* p = w;
    w += (bytes + 255) & ~(size_t)255;
    return p;
  };
  uint32_t* X   = (uint32_t*)alloc((size_t)N * 128 * 2);  // h, sliced [8][N][8 u32]
  uint32_t* U   = (uint32_t*)alloc((size_t)N * 128 * 2);  // pos agg, sliced
  uint32_t* V   = (uint32_t*)alloc((size_t)N * 128 * 2);  // neg agg, sliced
  u16* wt       = (u16*)alloc((size_t)L * 2 * 128 * 128 * 2);
  uint32_t* rec = (uint32_t*)alloc(((size_t)E + 32) * 4);
  int* cnt      = (int*)alloc((size_t)M * 4);
  int* offs     = (int*)alloc((size_t)(M + 1) * 4);
  int* cur      = (int*)alloc((size_t)M * 4);
  int* bnd      = (int*)alloc((size_t)(N + 1) * 4);
  int* part     = (int*)alloc(1024 * 4);
  float* dpn    = (float*)alloc((size_t)N * 8);
  float* pooled = (float*)alloc((size_t)G * 128 * 4);
  float* gcnt   = (float*)alloc((size_t)G * 4);

  hipMemsetAsync(cnt, 0, (size_t)M * 4, stream);
  hipMemsetAsync(pooled, 0, (size_t)G * 128 * 4, stream);
  hipMemsetAsync(gcnt, 0, (size_t)G * 4, stream);

  int n4 = N * 32;
  k_cvt_x<<<(n4 + 255) / 256, 256, 0, stream>>>(x, X, n4, N);
  int wtot = L * 2 * 128 * 128;
  k_cvt_w<<<(wtot + 255) / 256, 256, 0, stream>>>(Wp, Wn, wt, wtot);
  k_count<<<(E + 255) / 256, 256, 0, stream>>>(ei, ew, cnt, E);
  int NB = (M + 1023) / 1024;
  k_scan1<<<NB, 1024, 0, stream>>>(cnt, offs, part, M);
  k_scan2<<<1, 1024, 0, stream>>>(part, offs, rec, NB, M);
  k_scan3<<<(N + 255) / 256, 256, 0, stream>>>(offs, part, cur, bnd, dpn, N, M);
  k_build<<<(E + 255) / 256, 256, 0, stream>>>(ei, ew, cur, rec, E);

  int nchunks = (N + 127) / 128;
  int aggblocks = 8 * ((N + 3) / 4);
  for (int l = 0; l < L; ++l) {
    k_agg<<<aggblocks, 256, 0, stream>>>(X, bnd, rec, dpn, U, V, N);
    k_gemm<<<512, 256, 0, stream>>>((const short*)U, (const short*)V,
                                    wt + (size_t)l * 32768, bp + (size_t)l * 128,
                                    bn + (size_t)l * 128, (u16*)X, N, nchunks);
  }
  k_pool<<<(((N + 7) / 8) * 64 + 255) / 256, 256, 0, stream>>>(X, bt, pooled, gcnt, N);
  k_ln<<<(G * 64 + 255) / 256, 256, 0, stream>>>(pooled, gcnt, gamma, beta, (float*)d_out, G);
}